// Round 1
// baseline (234.782 us; speedup 1.0000x reference)
//
#include <hip/hip_runtime.h>
#include <hip/hip_bf16.h>

// Problem constants
#define BB   8
#define NNODE 128
#define CIN  512
#define HH   8
#define DDIM 64
#define HD   512   // H*D

typedef float f32x4 __attribute__((ext_vector_type(4)));
typedef short bf16x8 __attribute__((ext_vector_type(8)));

static __device__ __forceinline__ unsigned short f2bf(float f) {
    // round-to-nearest-even f32 -> bf16 (inputs are finite)
    unsigned int x = __float_as_uint(f);
    x = x + 0x7FFFu + ((x >> 16) & 1u);
    return (unsigned short)(x >> 16);
}

// ---------------------------------------------------------------------------
// Kernel 1: transpose + convert the 4 weight matrices [c][hd] f32 -> [hd][c] bf16
// WT layout: [m][hd][c], m: 0=We, 1=Wq, 2=Wk, 3=Wv
// ---------------------------------------------------------------------------
__global__ __launch_bounds__(256) void k_wt(
    const float* __restrict__ We, const float* __restrict__ Wq,
    const float* __restrict__ Wk, const float* __restrict__ Wv,
    unsigned short* __restrict__ WT)
{
    const int hd = blockIdx.x;          // 0..511
    const int m  = blockIdx.y;          // 0..3
    const float* W = (m == 0) ? We : (m == 1) ? Wq : (m == 2) ? Wk : Wv;
    const int c0 = threadIdx.x * 2;
    unsigned int lo = f2bf(W[(size_t)c0 * HD + hd]);
    unsigned int hi = f2bf(W[(size_t)(c0 + 1) * HD + hd]);
    *reinterpret_cast<unsigned int*>(&WT[((size_t)m * HD + hd) * CIN + c0]) = lo | (hi << 16);
}

// ---------------------------------------------------------------------------
// Kernel 2: QKV projections via bf16 MFMA.
// grid (16 row-tiles, 8 col-tiles, 3 matrices), block 256 (4 waves).
// Block computes 64 rows x 64 cols. Wave w: rows [w*16, w*16+16).
// Q/K/V out f32 layout [row(b*128+n)][hd]; K scaled by D^-0.5.
// ---------------------------------------------------------------------------
__global__ __launch_bounds__(256) void k_qkv(
    const float* __restrict__ hin,
    const unsigned short* __restrict__ WT,
    const float* __restrict__ bq, const float* __restrict__ bk, const float* __restrict__ bv,
    float* __restrict__ Qo, float* __restrict__ Ko, float* __restrict__ Vo)
{
    __shared__ unsigned short hs[64][520];   // 64 rows x 512 c (bf16), +8 pad
    const int rt = blockIdx.x;   // row tile
    const int ct = blockIdx.y;   // col tile
    const int m  = blockIdx.z;   // 0=Q,1=K,2=V
    const int t  = threadIdx.x;
    const int w  = t >> 6;
    const int l  = t & 63;
    const int g  = l >> 4;
    const int c15 = l & 15;
    const float* bias = (m == 0) ? bq : (m == 1) ? bk : bv;
    float* Out = (m == 0) ? Qo : (m == 1) ? Ko : Vo;
    const unsigned short* Wm = WT + (size_t)(m + 1) * HD * CIN;  // Wq/Wk/Wv slices
    const int rowbase = rt * 64;
    const int colbase = ct * 64;

    // stage 64 h-rows, f32 -> bf16
#pragma unroll
    for (int q = 0; q < 32; ++q) {
        int f = q * 1024 + t * 4;        // 0..32767
        int row = f >> 9;
        int c = f & 511;
        f32x4 hv = *reinterpret_cast<const f32x4*>(hin + (size_t)(rowbase + row) * CIN + c);
        unsigned long long pk =
            (unsigned long long)f2bf(hv[0]) |
            ((unsigned long long)f2bf(hv[1]) << 16) |
            ((unsigned long long)f2bf(hv[2]) << 32) |
            ((unsigned long long)f2bf(hv[3]) << 48);
        *reinterpret_cast<unsigned long long*>(&hs[row][c]) = pk;
    }
    __syncthreads();

    f32x4 acc[4];
#pragma unroll
    for (int nf = 0; nf < 4; ++nf) acc[nf] = (f32x4){0.f, 0.f, 0.f, 0.f};

#pragma unroll
    for (int kt = 0; kt < 16; ++kt) {
        bf16x8 afr = *reinterpret_cast<const bf16x8*>(&hs[w * 16 + c15][kt * 32 + g * 8]);
#pragma unroll
        for (int nf = 0; nf < 4; ++nf) {
            const unsigned short* wp = Wm + (size_t)(colbase + nf * 16 + c15) * CIN + kt * 32 + g * 8;
            bf16x8 bfr = *reinterpret_cast<const bf16x8*>(wp);
            acc[nf] = __builtin_amdgcn_mfma_f32_16x16x32_bf16(afr, bfr, acc[nf], 0, 0, 0);
        }
    }

    const float scale = (m == 1) ? 0.125f : 1.0f;   // D^-0.5 on K
#pragma unroll
    for (int nf = 0; nf < 4; ++nf) {
        int col = colbase + nf * 16 + c15;
        float bv_ = bias[col];
#pragma unroll
        for (int r = 0; r < 4; ++r) {
            int row = rowbase + w * 16 + g * 4 + r;
            Out[(size_t)row * HD + col] = (acc[nf][r] + bv_) * scale;
        }
    }
}

// ---------------------------------------------------------------------------
// Kernel 3: main fused kernel. One block per (b,i); 512 threads = 8 waves,
// wave w == head h. Stages e[b,i,:,:] in 4 c-chunks (double-buffered bf16 LDS),
// MFMAs against WeT, epilogue: scores -> exp/clip -> *k_RW -> PV + denom -> out.
// ---------------------------------------------------------------------------
__global__ __launch_bounds__(512, 2) void k_main(
    const float* __restrict__ e, const float* __restrict__ k_RW,
    const unsigned short* __restrict__ WT,   // We slice at offset 0: [hd][c] bf16
    const float* __restrict__ be,
    const float* __restrict__ Qw, const float* __restrict__ Kw, const float* __restrict__ Vw,
    float* __restrict__ out)
{
    __shared__ unsigned short e_s[2][128][136];  // 2 bufs x 128 j x 128 c (+8 pad)
    __shared__ float s_lds[8][128];

    const int bi = blockIdx.x;        // b*128 + i
    const int b  = bi >> 7;
    const int t  = threadIdx.x;
    const int h  = t >> 6;            // wave id == head
    const int l  = t & 63;
    const int g  = l >> 4;
    const int c15 = l & 15;

    const float* ebase = e + (size_t)bi * (NNODE * CIN);

    f32x4 acc[8][4];
#pragma unroll
    for (int jm = 0; jm < 8; ++jm)
#pragma unroll
        for (int dc = 0; dc < 4; ++dc)
            acc[jm][dc] = (f32x4){0.f, 0.f, 0.f, 0.f};

    // per-lane Q row and be slice for this head
    float q_l[4], be_l[4];
#pragma unroll
    for (int dc = 0; dc < 4; ++dc) {
        q_l[dc]  = Qw[(size_t)bi * HD + h * 64 + dc * 16 + c15];
        be_l[dc] = be[h * 64 + dc * 16 + c15];
    }

    f32x4 st[8];

    // prologue: load + write chunk 0
#pragma unroll
    for (int q = 0; q < 8; ++q) {
        int f = q * 2048 + t * 4;     // 0..16383
        int row = f >> 7;
        int c = f & 127;
        st[q] = *reinterpret_cast<const f32x4*>(ebase + (size_t)row * CIN + c);
    }
#pragma unroll
    for (int q = 0; q < 8; ++q) {
        int f = q * 2048 + t * 4;
        int row = f >> 7;
        int c = f & 127;
        unsigned long long pk =
            (unsigned long long)f2bf(st[q][0]) |
            ((unsigned long long)f2bf(st[q][1]) << 16) |
            ((unsigned long long)f2bf(st[q][2]) << 32) |
            ((unsigned long long)f2bf(st[q][3]) << 48);
        *reinterpret_cast<unsigned long long*>(&e_s[0][row][c]) = pk;
    }
    __syncthreads();

    for (int cc = 0; cc < 4; ++cc) {
        const int buf = cc & 1;
        // issue next chunk's global loads early (hide HBM under MFMA)
        if (cc < 3) {
#pragma unroll
            for (int q = 0; q < 8; ++q) {
                int f = q * 2048 + t * 4;
                int row = f >> 7;
                int c = f & 127;
                st[q] = *reinterpret_cast<const f32x4*>(ebase + (size_t)row * CIN + (cc + 1) * 128 + c);
            }
        }
        // compute current chunk: 128 MFMAs per wave
#pragma unroll
        for (int kt = 0; kt < 4; ++kt) {
            bf16x8 bfr[4];
#pragma unroll
            for (int dc = 0; dc < 4; ++dc) {
                const unsigned short* wp = WT + (size_t)(h * 64 + dc * 16 + c15) * CIN + cc * 128 + kt * 32 + g * 8;
                bfr[dc] = *reinterpret_cast<const bf16x8*>(wp);
            }
#pragma unroll
            for (int jm = 0; jm < 8; ++jm) {
                bf16x8 afr = *reinterpret_cast<const bf16x8*>(&e_s[buf][jm * 16 + c15][kt * 32 + g * 8]);
#pragma unroll
                for (int dc = 0; dc < 4; ++dc) {
                    acc[jm][dc] = __builtin_amdgcn_mfma_f32_16x16x32_bf16(afr, bfr[dc], acc[jm][dc], 0, 0, 0);
                }
            }
        }
        // write next chunk into the other buffer
        if (cc < 3) {
#pragma unroll
            for (int q = 0; q < 8; ++q) {
                int f = q * 2048 + t * 4;
                int row = f >> 7;
                int c = f & 127;
                unsigned long long pk =
                    (unsigned long long)f2bf(st[q][0]) |
                    ((unsigned long long)f2bf(st[q][1]) << 16) |
                    ((unsigned long long)f2bf(st[q][2]) << 32) |
                    ((unsigned long long)f2bf(st[q][3]) << 48);
                *reinterpret_cast<unsigned long long*>(&e_s[buf ^ 1][row][c]) = pk;
            }
        }
        __syncthreads();
    }

    // epilogue: scores s[h][j] = sum_d (E + be) * Q * K ; exp(clip) * k_RW
    const float* Kb  = Kw + (size_t)b * NNODE * HD;
    const float* krw = k_RW + (size_t)bi * NNODE;
#pragma unroll
    for (int jm = 0; jm < 8; ++jm) {
        float p[4];
#pragma unroll
        for (int r = 0; r < 4; ++r) {
            int j = jm * 16 + g * 4 + r;
            float s = 0.f;
#pragma unroll
            for (int dc = 0; dc < 4; ++dc) {
                float ev = acc[jm][dc][r] + be_l[dc];
                float kv = Kb[(size_t)j * HD + h * 64 + dc * 16 + c15];
                s += ev * q_l[dc] * kv;
            }
            p[r] = s;
        }
#pragma unroll
        for (int r = 0; r < 4; ++r) {
            float v = p[r];
            v += __shfl_xor(v, 1);
            v += __shfl_xor(v, 2);
            v += __shfl_xor(v, 4);
            v += __shfl_xor(v, 8);
            int j = jm * 16 + g * 4 + r;
            float sv = fminf(fmaxf(v, -5.f), 5.f);
            sv = expf(sv) * krw[j];
            if (c15 == 0) s_lds[h][j] = sv;
        }
    }
    __syncthreads();

    // PV + denom; lane = d
    const float* Vb = Vw + (size_t)b * NNODE * HD;
    const int d = l;
    float o0 = 0.f, den = 0.f;
#pragma unroll 4
    for (int j = 0; j < NNODE; ++j) {
        float sv = s_lds[h][j];
        o0 = fmaf(sv, Vb[(size_t)j * HD + h * 64 + d], o0);
        den += sv;
    }
    den = fmaxf(den, 1e-6f);
    out[(size_t)bi * HD + h * 64 + d] = o0 / den;
}

// ---------------------------------------------------------------------------
extern "C" void kernel_launch(void* const* d_in, const int* in_sizes, int n_in,
                              void* d_out, int out_size, void* d_ws, size_t ws_size,
                              hipStream_t stream) {
    const float* hin = (const float*)d_in[0];
    const float* e   = (const float*)d_in[1];
    const float* krw = (const float*)d_in[2];
    const float* Wq  = (const float*)d_in[3];
    const float* bq  = (const float*)d_in[4];
    const float* Wk  = (const float*)d_in[5];
    const float* bk  = (const float*)d_in[6];
    const float* We  = (const float*)d_in[7];
    const float* be  = (const float*)d_in[8];
    const float* Wv  = (const float*)d_in[9];
    const float* bv  = (const float*)d_in[10];
    float* out = (float*)d_out;

    char* ws = (char*)d_ws;
    unsigned short* WT = (unsigned short*)ws;                 // 4*512*512 bf16 = 2 MB
    float* Q = (float*)(ws + (2ull << 20));                   // 2 MB
    float* K = (float*)(ws + (4ull << 20));                   // 2 MB
    float* V = (float*)(ws + (6ull << 20));                   // 2 MB

    k_wt<<<dim3(512, 4), dim3(256), 0, stream>>>(We, Wq, Wk, Wv, WT);
    k_qkv<<<dim3(16, 8, 3), dim3(256), 0, stream>>>(hin, WT, bq, bk, bv, Q, K, V);
    k_main<<<dim3(1024), dim3(512), 0, stream>>>(e, krw, WT, be, Q, K, V, out);
}